// Round 3
// baseline (10005.117 us; speedup 1.0000x reference)
//
#include <hip/hip_runtime.h>

#define NTOK 49
#define CDIM 384
#define HEADS 12
#define HD 32
#define NWIN 64
#define NQKV 1152
#define SCALE 0.17677669529663687f  // 32^-0.5

typedef __attribute__((ext_vector_type(8))) __bf16 bf16x8;
typedef __attribute__((ext_vector_type(4))) float f32x4;

// workspace offsets (bytes), all 256-aligned
#define OFF_WQKVT   0ull                 // 1152*384 bf16 = 884736
#define OFF_WOUTT   884736ull            // 384*384 bf16  = 294912
#define OFF_ADDEND  1179648ull           // 64*12*49*49 f32 = 7375872
#define OFF_ATTNOUT 8555520ull           // B*49*384 bf16 = 154140672

// ---------------- prep kernels ----------------

__global__ void prep_weights(const float* __restrict__ Wqkv, const float* __restrict__ Wout,
                             __bf16* __restrict__ WqkvT, __bf16* __restrict__ WoutT) {
    int idx = blockIdx.x * 256 + threadIdx.x;
    if (idx < NQKV * CDIM) {
        int n = idx / CDIM, k = idx % CDIM;
        WqkvT[idx] = (__bf16)Wqkv[(size_t)k * NQKV + n];
    }
    if (idx < CDIM * CDIM) {
        int n = idx / CDIM, k = idx % CDIM;
        WoutT[idx] = (__bf16)Wout[(size_t)k * CDIM + n];
    }
}

__global__ void prep_addend(const float* __restrict__ rpb, const int* __restrict__ rel,
                            const float* __restrict__ mask, float* __restrict__ addend) {
    int idx = blockIdx.x * 256 + threadIdx.x;
    if (idx >= NWIN * HEADS * NTOK * NTOK) return;
    int mn = idx % (NTOK * NTOK);
    int h  = (idx / (NTOK * NTOK)) % HEADS;
    int w  = idx / (NTOK * NTOK * HEADS);
    addend[idx] = rpb[rel[mn] * HEADS + h] + mask[(size_t)w * NTOK * NTOK + mn];
}

// ---------------- fused qkv + attention ----------------
// one block per window; 512 threads = 8 waves; 6 groups of 2 heads.
// All MFMA operands fragment-linear in LDS: frag[tile][lane][8] -> reads base+lane*16.
// LDS: xs 49152 + qk/ps union 16384 + vt 8192 = 73728 B -> 2 blocks/CU.
// QKV units: wave w -> n-tile w (4 m-tiles, B reused x4) + n-tile 8+(w>>1) (2 m-tiles).

__global__ __launch_bounds__(512, 2) void fused_qkv_attn(
    const float* __restrict__ x, const float* __restrict__ bqkv,
    const __bf16* __restrict__ WqkvT, const float* __restrict__ addend,
    __bf16* __restrict__ attnout)
{
    __shared__ __attribute__((aligned(16))) __bf16 xs[4 * 12 * 512];   // x frags [mt][kb][slot][8], slot = lane^(kb&7)
    __shared__ __attribute__((aligned(16))) __bf16 qkps[8192];         // q: [0,4096) [hl][mt][lane][8]; k: [4096,8192)
                                                                       // ps overlays all: [hl][mt][kb][lane][8]
    __shared__ __attribute__((aligned(16))) __bf16 vt[2 * 2 * 2 * 512];// [hl][dt][kb][lane][8]

    const int b    = blockIdx.x;
    const int tid  = threadIdx.x;
    const int wave = tid >> 6, lane = tid & 63;
    const int l15  = lane & 15, l4 = lane >> 4;
    const int w    = b & (NWIN - 1);

    // ---- phase 0: stage x -> bf16 fragment-linear LDS ----
    {
        // zero pad rows 49..63 (mt=3, row-part != 0)
        for (int i = tid; i < 12 * 64; i += 512) {
            int kb = i >> 6, lp = i & 63;
            if (lp & 15) {
                int slot = lp ^ (kb & 7);
                *reinterpret_cast<int4*>(&xs[((36 + kb) * 64 + slot) * 8]) = int4{0, 0, 0, 0};
            }
        }
        const float* xw = x + (size_t)b * NTOK * CDIM;
        for (int i = tid; i < NTOK * CDIM / 4; i += 512) {
            float4 v = reinterpret_cast<const float4*>(xw)[i];
            int e = i * 4;
            int row = e / CDIM, c = e % CDIM;
            int mt = row >> 4, kb = c >> 5;
            int lp = (row & 15) + 16 * ((c & 31) >> 3);
            int slot = lp ^ (kb & 7);
            union { __bf16 h[4]; uint2 u; } t;
            t.h[0] = (__bf16)v.x; t.h[1] = (__bf16)v.y; t.h[2] = (__bf16)v.z; t.h[3] = (__bf16)v.w;
            *reinterpret_cast<uint2*>(&xs[((mt * 12 + kb) * 64 + slot) * 8 + (c & 7)]) = t.u;
        }
    }
    __syncthreads();

    for (int g = 0; g < 6; ++g) {
        // ---- QKV gemm: 48 cells (12 n-tiles x 4 mt); wave w: tile w (4 mt) + tile 8+(w>>1) (2 mt) ----
        {
            const int nA = wave;
            const int hlA = nA / 6, remA = nA % 6;
            const int whichA = remA >> 1, subA = remA & 1;
            const int wcolA = whichA * CDIM + (g * 2 + hlA) * HD + subA * 16 + l15;
            const __bf16* bptrA = WqkvT + (size_t)wcolA * CDIM + l4 * 8;

            const int nB = 8 + (wave >> 1);
            const int hlB = 1, remB = nB % 6;
            const int whichB = remB >> 1, subB = remB & 1;
            const int wcolB = whichB * CDIM + (g * 2 + hlB) * HD + subB * 16 + l15;
            const __bf16* bptrB = WqkvT + (size_t)wcolB * CDIM + l4 * 8;
            const int mtB = (wave & 1) * 2;

            float biasA = bqkv[wcolA];
            float biasB = bqkv[wcolB];

            f32x4 accA[4] = {};
            f32x4 accB[2] = {};
            for (int kb = 0; kb < 12; ++kb) {
                int slot = lane ^ (kb & 7);
                bf16x8 bfA = *reinterpret_cast<const bf16x8*>(bptrA + kb * 32);
                bf16x8 bfB = *reinterpret_cast<const bf16x8*>(bptrB + kb * 32);
                bf16x8 af[4];
#pragma unroll
                for (int mt = 0; mt < 4; ++mt)
                    af[mt] = *reinterpret_cast<const bf16x8*>(&xs[((mt * 12 + kb) * 64 + slot) * 8]);
#pragma unroll
                for (int mt = 0; mt < 4; ++mt)
                    accA[mt] = __builtin_amdgcn_mfma_f32_16x16x32_bf16(af[mt], bfA, accA[mt], 0, 0, 0);
#pragma unroll
                for (int i = 0; i < 2; ++i)
                    accB[i] = __builtin_amdgcn_mfma_f32_16x16x32_bf16(af[mtB + i], bfB, accB[i], 0, 0, 0);
            }

            auto store_qkv = [&](int which, int sub, int hl, int mt, const f32x4& a, float bias) {
                float scl = (which == 0) ? SCALE : 1.0f;
#pragma unroll
                for (int r = 0; r < 4; ++r) {
                    float vv = (a[r] + bias) * scl;
                    __bf16 bv = (__bf16)vv;
                    int mrow = l4 * 4 + r;
                    if (which == 2) {
                        int tok = mt * 16 + mrow;
                        vt[(((hl * 2 + sub) * 2 + (tok >> 5)) * 64 + (l15 + 16 * ((tok & 31) >> 3))) * 8 + (tok & 7)] = bv;
                    } else {
                        int base = (which == 1) ? 4096 : 0;
                        qkps[base + ((hl * 4 + mt) * 64 + (mrow + 16 * (sub * 2 + (l15 >> 3)))) * 8 + (l15 & 7)] = bv;
                    }
                }
            };
#pragma unroll
            for (int mt = 0; mt < 4; ++mt)
                store_qkv(whichA, subA, hlA, mt, accA[mt], biasA);
#pragma unroll
            for (int i = 0; i < 2; ++i)
                store_qkv(whichB, subB, hlB, mtB + i, accB[i], biasB);
        }
        __syncthreads();   // bar A: q/k/vt ready

        // ---- attention: wave -> head hl = wave>>2, m-tile mt = wave&3 ----
        {
            int hl = wave >> 2, mt = wave & 3;
            int h = g * 2 + hl;
            const float* add_h = addend + (size_t)(w * HEADS + h) * (NTOK * NTOK);

            // prefetch bias+mask addend (global; latency hides under S MFMAs)
            float adds[4][4];
#pragma unroll
            for (int r = 0; r < 4; ++r) {
                int m = mt * 16 + l4 * 4 + r;
#pragma unroll
                for (int nt = 0; nt < 4; ++nt) {
                    int n = nt * 16 + l15;
                    adds[r][nt] = (m < NTOK && n < NTOK) ? add_h[m * NTOK + n] : 0.0f;
                }
            }

            // S = q k^T  (K=32 -> 1 MFMA per n-tile)
            bf16x8 aq = *reinterpret_cast<const bf16x8*>(&qkps[(hl * 4 + mt) * 512 + lane * 8]);
            f32x4 s[4];
#pragma unroll
            for (int nt = 0; nt < 4; ++nt) {
                bf16x8 bk = *reinterpret_cast<const bf16x8*>(&qkps[4096 + (hl * 4 + nt) * 512 + lane * 8]);
                f32x4 z = {};
                s[nt] = __builtin_amdgcn_mfma_f32_16x16x32_bf16(aq, bk, z, 0, 0, 0);
            }
            __syncthreads();   // bar B: all q/k reads done; ps may overwrite

#pragma unroll
            for (int r = 0; r < 4; ++r) {
                float vals[4];
#pragma unroll
                for (int nt = 0; nt < 4; ++nt) {
                    int n = nt * 16 + l15;
                    vals[nt] = (n < NTOK) ? (s[nt][r] + adds[r][nt]) : -1e30f;
                }
                float mx = fmaxf(fmaxf(vals[0], vals[1]), fmaxf(vals[2], vals[3]));
                mx = fmaxf(mx, __shfl_xor(mx, 1));
                mx = fmaxf(mx, __shfl_xor(mx, 2));
                mx = fmaxf(mx, __shfl_xor(mx, 4));
                mx = fmaxf(mx, __shfl_xor(mx, 8));
                float e0 = __expf(vals[0] - mx);
                float e1 = __expf(vals[1] - mx);
                float e2 = __expf(vals[2] - mx);
                float e3 = __expf(vals[3] - mx);
                float sum = (e0 + e1) + (e2 + e3);
                sum += __shfl_xor(sum, 1);
                sum += __shfl_xor(sum, 2);
                sum += __shfl_xor(sum, 4);
                sum += __shfl_xor(sum, 8);
                float inv = 1.0f / sum;
                float ev[4] = {e0, e1, e2, e3};
#pragma unroll
                for (int nt = 0; nt < 4; ++nt) {
                    int lp = (l4 * 4 + r) + 16 * ((nt & 1) * 2 + (l15 >> 3));
                    int kb = nt >> 1;
                    qkps[(((hl * 4 + mt) * 2 + kb) * 64 + lp) * 8 + (l15 & 7)] = (__bf16)(ev[nt] * inv);
                }
            }

            // PV (same wave reads its own ps region)
            f32x4 o[2] = {};
#pragma unroll
            for (int kb = 0; kb < 2; ++kb) {
                bf16x8 ap = *reinterpret_cast<const bf16x8*>(&qkps[((hl * 4 + mt) * 2 + kb) * 512 + lane * 8]);
#pragma unroll
                for (int dt = 0; dt < 2; ++dt) {
                    bf16x8 bv = *reinterpret_cast<const bf16x8*>(&vt[((hl * 2 + dt) * 2 + kb) * 512 + lane * 8]);
                    o[dt] = __builtin_amdgcn_mfma_f32_16x16x32_bf16(ap, bv, o[dt], 0, 0, 0);
                }
            }
#pragma unroll
            for (int dt = 0; dt < 2; ++dt) {
                int col = h * HD + dt * 16 + l15;
#pragma unroll
                for (int r = 0; r < 4; ++r) {
                    int tok = mt * 16 + l4 * 4 + r;
                    if (tok < NTOK)
                        attnout[((size_t)b * NTOK + tok) * CDIM + col] = (__bf16)o[dt][r];
                }
            }
        }
        __syncthreads();   // bar C: ps/vt reads done before next group's writes
    }
}

// ---------------- out projection: [M=B*49, 384] @ [384,384] + b ----------------

__global__ __launch_bounds__(256, 3) void out_proj(
    const __bf16* __restrict__ A, const __bf16* __restrict__ WoutT,
    const float* __restrict__ bout, float* __restrict__ out)
{
    __shared__ __attribute__((aligned(16))) __bf16 as[4 * 12 * 512];   // frags [mt][kb][slot][8]
    const int blk = blockIdx.x, tid = threadIdx.x;
    const int wave = tid >> 6, lane = tid & 63;
    const int l15 = lane & 15, l4 = lane >> 4;

    const __bf16* Ab = A + (size_t)blk * 64 * CDIM;
    for (int i = tid; i < 64 * CDIM / 8; i += 256) {
        int4 ld = reinterpret_cast<const int4*>(Ab)[i];
        int e = i * 8;
        int row = e / CDIM, c = e % CDIM;
        int mt = row >> 4, kb = c >> 5;
        int lp = (row & 15) + 16 * ((c & 31) >> 3);
        int slot = lp ^ (kb & 7);
        *reinterpret_cast<int4*>(&as[((mt * 12 + kb) * 64 + slot) * 8]) = ld;
    }
    __syncthreads();

    f32x4 acc[6][4] = {};
    for (int kb = 0; kb < 12; ++kb) {
        int slot = lane ^ (kb & 7);
        bf16x8 af[4];
#pragma unroll
        for (int mt = 0; mt < 4; ++mt)
            af[mt] = *reinterpret_cast<const bf16x8*>(&as[((mt * 12 + kb) * 64 + slot) * 8]);
#pragma unroll
        for (int j = 0; j < 6; ++j) {
            int col = (wave * 6 + j) * 16 + l15;
            bf16x8 bf = *reinterpret_cast<const bf16x8*>(WoutT + (size_t)col * CDIM + kb * 32 + l4 * 8);
#pragma unroll
            for (int mt = 0; mt < 4; ++mt)
                acc[j][mt] = __builtin_amdgcn_mfma_f32_16x16x32_bf16(af[mt], bf, acc[j][mt], 0, 0, 0);
        }
    }
#pragma unroll
    for (int j = 0; j < 6; ++j) {
        int col = (wave * 6 + j) * 16 + l15;
        float bias = bout[col];
#pragma unroll
        for (int mt = 0; mt < 4; ++mt) {
#pragma unroll
            for (int r = 0; r < 4; ++r) {
                size_t row = (size_t)blk * 64 + mt * 16 + l4 * 4 + r;
                out[row * CDIM + col] = acc[j][mt][r] + bias;
            }
        }
    }
}

// ---------------- launch ----------------

extern "C" void kernel_launch(void* const* d_in, const int* in_sizes, int n_in,
                              void* d_out, int out_size, void* d_ws, size_t ws_size,
                              hipStream_t stream) {
    (void)n_in; (void)out_size; (void)ws_size;
    const float* x    = (const float*)d_in[0];
    const float* mask = (const float*)d_in[1];
    const float* Wqkv = (const float*)d_in[2];
    const float* bqkv = (const float*)d_in[3];
    const float* Wout = (const float*)d_in[4];
    const float* bout = (const float*)d_in[5];
    const float* rpb  = (const float*)d_in[6];
    const int*   rel  = (const int*)d_in[7];

    const int B = in_sizes[0] / (NTOK * CDIM);   // 4096

    char* ws = (char*)d_ws;
    __bf16* WqkvT   = (__bf16*)(ws + OFF_WQKVT);
    __bf16* WoutT   = (__bf16*)(ws + OFF_WOUTT);
    float*  addend  = (float*)(ws + OFF_ADDEND);
    __bf16* attnout = (__bf16*)(ws + OFF_ATTNOUT);
    float*  out     = (float*)d_out;

    prep_weights<<<(NQKV * CDIM + 255) / 256, 256, 0, stream>>>(Wqkv, Wout, WqkvT, WoutT);
    prep_addend<<<(NWIN * HEADS * NTOK * NTOK + 255) / 256, 256, 0, stream>>>(rpb, rel, mask, addend);
    fused_qkv_attn<<<B, 512, 0, stream>>>(x, bqkv, WqkvT, addend, attnout);
    out_proj<<<(B * NTOK) / 64, 256, 0, stream>>>(attnout, WoutT, bout, out);
}

// Round 4
// 2430.500 us; speedup vs baseline: 4.1165x; 4.1165x over previous
//
#include <hip/hip_runtime.h>

#define NTOK 49
#define CDIM 384
#define HEADS 12
#define HD 32
#define NWIN 64
#define NQKV 1152
#define SCALE 0.17677669529663687f  // 32^-0.5

typedef __attribute__((ext_vector_type(8))) __bf16 bf16x8;
typedef __attribute__((ext_vector_type(4))) float f32x4;

// workspace offsets (bytes), all 256-aligned
#define OFF_WQKVT   0ull                 // 1152*384 bf16 = 884736
#define OFF_WOUTT   884736ull            // 384*384 bf16  = 294912
#define OFF_ADDEND  1179648ull           // 64*12*49*49 f32 = 7375872
#define OFF_ATTNOUT 8555520ull           // B*49*384 bf16 = 154140672

// ---------------- prep kernels ----------------

__global__ void prep_weights(const float* __restrict__ Wqkv, const float* __restrict__ Wout,
                             __bf16* __restrict__ WqkvT, __bf16* __restrict__ WoutT) {
    int idx = blockIdx.x * 256 + threadIdx.x;
    if (idx < NQKV * CDIM) {
        int n = idx / CDIM, k = idx % CDIM;
        WqkvT[idx] = (__bf16)Wqkv[(size_t)k * NQKV + n];
    }
    if (idx < CDIM * CDIM) {
        int n = idx / CDIM, k = idx % CDIM;
        WoutT[idx] = (__bf16)Wout[(size_t)k * CDIM + n];
    }
}

__global__ void prep_addend(const float* __restrict__ rpb, const int* __restrict__ rel,
                            const float* __restrict__ mask, float* __restrict__ addend) {
    int idx = blockIdx.x * 256 + threadIdx.x;
    if (idx >= NWIN * HEADS * NTOK * NTOK) return;
    int mn = idx % (NTOK * NTOK);
    int h  = (idx / (NTOK * NTOK)) % HEADS;
    int w  = idx / (NTOK * NTOK * HEADS);
    addend[idx] = rpb[rel[mn] * HEADS + h] + mask[(size_t)w * NTOK * NTOK + mn];
}

// ---------------- fused qkv + attention ----------------
// one block per window; 512 threads = 8 waves; 6 groups of 2 heads.
// All MFMA operands stored in LDS as fragment-linear: frag[tile][lane][8] -> reads are base+lane*16.
// LDS: xs 49152 + qk/ps union 16384 + vt 8192 = 73728 B -> 2 blocks/CU.
// NOTE: plain __launch_bounds__(512) — the (512,4) variant capped VGPR at 64 and spilled ~1.3GB.

__global__ __launch_bounds__(512) void fused_qkv_attn(
    const float* __restrict__ x, const float* __restrict__ bqkv,
    const __bf16* __restrict__ WqkvT, const float* __restrict__ addend,
    __bf16* __restrict__ attnout)
{
    __shared__ __attribute__((aligned(16))) __bf16 xs[4 * 12 * 512];   // x frags [mt][kb][slot][8], slot = lane^(kb&7)
    __shared__ __attribute__((aligned(16))) __bf16 qkps[8192];         // q: [0,4096) [hl][mt][lane][8]; k: [4096,8192)
                                                                       // ps overlays all: [hl][mt][kb][lane][8]
    __shared__ __attribute__((aligned(16))) __bf16 vt[2 * 2 * 2 * 512];// [hl][dt][kb][lane][8]

    const int b    = blockIdx.x;
    const int tid  = threadIdx.x;
    const int wave = tid >> 6, lane = tid & 63;
    const int l15  = lane & 15, l4 = lane >> 4;
    const int w    = b & (NWIN - 1);

    // ---- phase 0: stage x -> bf16 fragment-linear LDS ----
    {
        // zero pad rows 49..63 (mt=3, row-part != 0)
        for (int i = tid; i < 12 * 64; i += 512) {
            int kb = i >> 6, lp = i & 63;
            if (lp & 15) {
                int slot = lp ^ (kb & 7);
                *reinterpret_cast<int4*>(&xs[((36 + kb) * 64 + slot) * 8]) = int4{0, 0, 0, 0};
            }
        }
        const float* xw = x + (size_t)b * NTOK * CDIM;
        for (int i = tid; i < NTOK * CDIM / 4; i += 512) {
            float4 v = reinterpret_cast<const float4*>(xw)[i];
            int e = i * 4;
            int row = e / CDIM, c = e % CDIM;
            int mt = row >> 4, kb = c >> 5;
            int lp = (row & 15) + 16 * ((c & 31) >> 3);
            int slot = lp ^ (kb & 7);
            union { __bf16 h[4]; uint2 u; } t;
            t.h[0] = (__bf16)v.x; t.h[1] = (__bf16)v.y; t.h[2] = (__bf16)v.z; t.h[3] = (__bf16)v.w;
            *reinterpret_cast<uint2*>(&xs[((mt * 12 + kb) * 64 + slot) * 8 + (c & 7)]) = t.u;
        }
    }
    __syncthreads();

    for (int g = 0; g < 6; ++g) {
        // ---- QKV gemm: 48 units (12 ncol-tiles x 4 mt), 6 per wave (all share mt = wave&3) ----
        {
            f32x4 acc[6] = {};
            const __bf16* bptr[6];
            int um[6];
#pragma unroll
            for (int i = 0; i < 6; ++i) {
                int u = wave + 8 * i;
                int mt = u & 3, n = u >> 2;          // n = hl*6 + which*2 + sub
                int hl = n / 6, rem = n % 6;
                int which = rem >> 1, sub = rem & 1;
                int h = g * 2 + hl;
                int wcol = which * CDIM + h * HD + sub * 16 + l15;
                bptr[i] = WqkvT + (size_t)wcol * CDIM + l4 * 8;
                um[i] = mt;
            }
            for (int kb = 0; kb < 12; ++kb) {
                int slot = lane ^ (kb & 7);
                bf16x8 bf[6], af[6];
#pragma unroll
                for (int i = 0; i < 6; ++i)
                    bf[i] = *reinterpret_cast<const bf16x8*>(bptr[i] + kb * 32);
#pragma unroll
                for (int i = 0; i < 6; ++i)
                    af[i] = *reinterpret_cast<const bf16x8*>(&xs[((um[i] * 12 + kb) * 64 + slot) * 8]);
#pragma unroll
                for (int i = 0; i < 6; ++i)
                    acc[i] = __builtin_amdgcn_mfma_f32_16x16x32_bf16(af[i], bf[i], acc[i], 0, 0, 0);
            }
            // write to fragment-linear q/k/vt
#pragma unroll
            for (int i = 0; i < 6; ++i) {
                int u = wave + 8 * i;
                int mt = u & 3, n = u >> 2;
                int hl = n / 6, rem = n % 6;
                int which = rem >> 1, sub = rem & 1;
                int h = g * 2 + hl;
                int wcol = which * CDIM + h * HD + sub * 16 + l15;
                float bias = bqkv[wcol];
                float scl = (which == 0) ? SCALE : 1.0f;
#pragma unroll
                for (int r = 0; r < 4; ++r) {
                    float vv = (acc[i][r] + bias) * scl;
                    __bf16 bv = (__bf16)vv;
                    int mrow = l4 * 4 + r;   // row within 16-tile
                    if (which == 2) {
                        int tok = mt * 16 + mrow;
                        int kb2 = tok >> 5;
                        int lp = l15 + 16 * ((tok & 31) >> 3);
                        vt[(((hl * 2 + sub) * 2 + kb2) * 64 + lp) * 8 + (tok & 7)] = bv;
                    } else {
                        int lp = mrow + 16 * (sub * 2 + (l15 >> 3));
                        int base = (which == 1) ? 4096 : 0;
                        qkps[base + ((hl * 4 + mt) * 64 + lp) * 8 + (l15 & 7)] = bv;
                    }
                }
            }
        }
        __syncthreads();   // bar A: q/k/vt ready

        // ---- attention: wave -> head hl = wave>>2, m-tile mt = wave&3 ----
        {
            int hl = wave >> 2, mt = wave & 3;
            int h = g * 2 + hl;

            // S = q k^T  (K=32 -> 1 MFMA per n-tile)
            bf16x8 aq = *reinterpret_cast<const bf16x8*>(&qkps[(hl * 4 + mt) * 512 + lane * 8]);
            f32x4 s[4];
#pragma unroll
            for (int nt = 0; nt < 4; ++nt) {
                bf16x8 bk = *reinterpret_cast<const bf16x8*>(&qkps[4096 + (hl * 4 + nt) * 512 + lane * 8]);
                f32x4 z = {};
                s[nt] = __builtin_amdgcn_mfma_f32_16x16x32_bf16(aq, bk, z, 0, 0, 0);
            }
            __syncthreads();   // bar B: all q/k reads done; ps may overwrite

            const float* add_h = addend + (size_t)(w * HEADS + h) * (NTOK * NTOK);
#pragma unroll
            for (int r = 0; r < 4; ++r) {
                int m = mt * 16 + l4 * 4 + r;
                float vals[4];
#pragma unroll
                for (int nt = 0; nt < 4; ++nt) {
                    int n = nt * 16 + l15;
                    float sv = s[nt][r];
                    if (n < NTOK) {
                        if (m < NTOK) sv += add_h[m * NTOK + n];
                    } else {
                        sv = -1e30f;
                    }
                    vals[nt] = sv;
                }
                float mx = fmaxf(fmaxf(vals[0], vals[1]), fmaxf(vals[2], vals[3]));
                mx = fmaxf(mx, __shfl_xor(mx, 1));
                mx = fmaxf(mx, __shfl_xor(mx, 2));
                mx = fmaxf(mx, __shfl_xor(mx, 4));
                mx = fmaxf(mx, __shfl_xor(mx, 8));
                float e0 = __expf(vals[0] - mx);
                float e1 = __expf(vals[1] - mx);
                float e2 = __expf(vals[2] - mx);
                float e3 = __expf(vals[3] - mx);
                float sum = (e0 + e1) + (e2 + e3);
                sum += __shfl_xor(sum, 1);
                sum += __shfl_xor(sum, 2);
                sum += __shfl_xor(sum, 4);
                sum += __shfl_xor(sum, 8);
                float inv = 1.0f / sum;
                float ev[4] = {e0, e1, e2, e3};
#pragma unroll
                for (int nt = 0; nt < 4; ++nt) {
                    int lp = (l4 * 4 + r) + 16 * ((nt & 1) * 2 + (l15 >> 3));
                    int kb = nt >> 1;
                    qkps[(((hl * 4 + mt) * 2 + kb) * 64 + lp) * 8 + (l15 & 7)] = (__bf16)(ev[nt] * inv);
                }
            }

            // PV (same wave reads its own ps region; compiler inserts lgkmcnt)
            f32x4 o[2] = {};
#pragma unroll
            for (int kb = 0; kb < 2; ++kb) {
                bf16x8 ap = *reinterpret_cast<const bf16x8*>(&qkps[((hl * 4 + mt) * 2 + kb) * 512 + lane * 8]);
#pragma unroll
                for (int dt = 0; dt < 2; ++dt) {
                    bf16x8 bv = *reinterpret_cast<const bf16x8*>(&vt[((hl * 2 + dt) * 2 + kb) * 512 + lane * 8]);
                    o[dt] = __builtin_amdgcn_mfma_f32_16x16x32_bf16(ap, bv, o[dt], 0, 0, 0);
                }
            }
#pragma unroll
            for (int dt = 0; dt < 2; ++dt) {
                int col = h * HD + dt * 16 + l15;
#pragma unroll
                for (int r = 0; r < 4; ++r) {
                    int tok = mt * 16 + l4 * 4 + r;
                    if (tok < NTOK)
                        attnout[((size_t)b * NTOK + tok) * CDIM + col] = (__bf16)o[dt][r];
                }
            }
        }
        __syncthreads();   // bar C: ps/vt reads done before next group's writes
    }
}

// ---------------- out projection: [M=B*49, 384] @ [384,384] + b ----------------
// block: 64 rows, 256 threads = 4 waves; wave w covers n-tiles 6w..6w+5
// A staged fragment-linear (conflict-free reads).

__global__ __launch_bounds__(256, 3) void out_proj(
    const __bf16* __restrict__ A, const __bf16* __restrict__ WoutT,
    const float* __restrict__ bout, float* __restrict__ out)
{
    __shared__ __attribute__((aligned(16))) __bf16 as[4 * 12 * 512];   // frags [mt][kb][slot][8]
    const int blk = blockIdx.x, tid = threadIdx.x;
    const int wave = tid >> 6, lane = tid & 63;
    const int l15 = lane & 15, l4 = lane >> 4;

    const __bf16* Ab = A + (size_t)blk * 64 * CDIM;
    for (int i = tid; i < 64 * CDIM / 8; i += 256) {
        int4 ld = reinterpret_cast<const int4*>(Ab)[i];
        int e = i * 8;
        int row = e / CDIM, c = e % CDIM;
        int mt = row >> 4, kb = c >> 5;
        int lp = (row & 15) + 16 * ((c & 31) >> 3);
        int slot = lp ^ (kb & 7);
        *reinterpret_cast<int4*>(&as[((mt * 12 + kb) * 64 + slot) * 8]) = ld;
    }
    __syncthreads();

    f32x4 acc[6][4] = {};
    for (int kb = 0; kb < 12; ++kb) {
        int slot = lane ^ (kb & 7);
        bf16x8 af[4];
#pragma unroll
        for (int mt = 0; mt < 4; ++mt)
            af[mt] = *reinterpret_cast<const bf16x8*>(&as[((mt * 12 + kb) * 64 + slot) * 8]);
#pragma unroll
        for (int j = 0; j < 6; ++j) {
            int col = (wave * 6 + j) * 16 + l15;
            bf16x8 bf = *reinterpret_cast<const bf16x8*>(WoutT + (size_t)col * CDIM + kb * 32 + l4 * 8);
#pragma unroll
            for (int mt = 0; mt < 4; ++mt)
                acc[j][mt] = __builtin_amdgcn_mfma_f32_16x16x32_bf16(af[mt], bf, acc[j][mt], 0, 0, 0);
        }
    }
#pragma unroll
    for (int j = 0; j < 6; ++j) {
        int col = (wave * 6 + j) * 16 + l15;
        float bias = bout[col];
#pragma unroll
        for (int mt = 0; mt < 4; ++mt) {
#pragma unroll
            for (int r = 0; r < 4; ++r) {
                size_t row = (size_t)blk * 64 + mt * 16 + l4 * 4 + r;
                out[row * CDIM + col] = acc[j][mt][r] + bias;
            }
        }
    }
}

// ---------------- launch ----------------

extern "C" void kernel_launch(void* const* d_in, const int* in_sizes, int n_in,
                              void* d_out, int out_size, void* d_ws, size_t ws_size,
                              hipStream_t stream) {
    (void)n_in; (void)out_size; (void)ws_size;
    const float* x    = (const float*)d_in[0];
    const float* mask = (const float*)d_in[1];
    const float* Wqkv = (const float*)d_in[2];
    const float* bqkv = (const float*)d_in[3];
    const float* Wout = (const float*)d_in[4];
    const float* bout = (const float*)d_in[5];
    const float* rpb  = (const float*)d_in[6];
    const int*   rel  = (const int*)d_in[7];

    const int B = in_sizes[0] / (NTOK * CDIM);   // 4096

    char* ws = (char*)d_ws;
    __bf16* WqkvT   = (__bf16*)(ws + OFF_WQKVT);
    __bf16* WoutT   = (__bf16*)(ws + OFF_WOUTT);
    float*  addend  = (float*)(ws + OFF_ADDEND);
    __bf16* attnout = (__bf16*)(ws + OFF_ATTNOUT);
    float*  out     = (float*)d_out;

    prep_weights<<<(NQKV * CDIM + 255) / 256, 256, 0, stream>>>(Wqkv, Wout, WqkvT, WoutT);
    prep_addend<<<(NWIN * HEADS * NTOK * NTOK + 255) / 256, 256, 0, stream>>>(rpb, rel, mask, addend);
    fused_qkv_attn<<<B, 512, 0, stream>>>(x, bqkv, WqkvT, addend, attnout);
    out_proj<<<(B * NTOK) / 64, 256, 0, stream>>>(attnout, WoutT, bout, out);
}

// Round 5
// 1881.653 us; speedup vs baseline: 5.3172x; 1.2917x over previous
//
#include <hip/hip_runtime.h>

#define NTOK 49
#define CDIM 384
#define HEADS 12
#define HD 32
#define NWIN 64
#define NQKV 1152
#define SCALE 0.17677669529663687f  // 32^-0.5

typedef __attribute__((ext_vector_type(8))) __bf16 bf16x8;
typedef __attribute__((ext_vector_type(4))) float f32x4;

// workspace offsets (bytes), all 256-aligned
#define OFF_WQKVT   0ull                 // 1152*384 bf16 = 884736
#define OFF_WOUTT   884736ull            // 384*384 bf16  = 294912
#define OFF_ADDEND  1179648ull           // 64*12*49*49 f32 = 7375872
#define OFF_QKVB    8555520ull           // 200704*1152 bf16 = 462422016
#define OFF_ATTNOUT 470977536ull         // 200704*384 bf16 = 154140672
// total ~625.1 MB

// ---------------- prep kernels ----------------

__global__ void prep_weights(const float* __restrict__ Wqkv, const float* __restrict__ Wout,
                             __bf16* __restrict__ WqkvT, __bf16* __restrict__ WoutT) {
    int idx = blockIdx.x * 256 + threadIdx.x;
    if (idx < NQKV * CDIM) {
        int n = idx / CDIM, k = idx % CDIM;
        WqkvT[idx] = (__bf16)Wqkv[(size_t)k * NQKV + n];
    }
    if (idx < CDIM * CDIM) {
        int n = idx / CDIM, k = idx % CDIM;
        WoutT[idx] = (__bf16)Wout[(size_t)k * CDIM + n];
    }
}

__global__ void prep_addend(const float* __restrict__ rpb, const int* __restrict__ rel,
                            const float* __restrict__ mask, float* __restrict__ addend) {
    int idx = blockIdx.x * 256 + threadIdx.x;
    if (idx >= NWIN * HEADS * NTOK * NTOK) return;
    int mn = idx % (NTOK * NTOK);
    int h  = (idx / (NTOK * NTOK)) % HEADS;
    int w  = idx / (NTOK * NTOK * HEADS);
    addend[idx] = rpb[rel[mn] * HEADS + h] + mask[(size_t)w * NTOK * NTOK + mn];
}

// ---------------- K1: qkv projection GEMM ----------------
// grid (M/64, 3): block = 64 rows x 384 cols (one of q/k/v). 512 thr = 8 waves.
// wave w: mt = w&3, 12 n-tiles starting at (w>>2)*12. One barrier per block.
// Writes qkv row-major bf16 [row][1152]; q gets bias+scale, k/v bias only.

__global__ __launch_bounds__(512) void qkv_gemm(
    const float* __restrict__ x, const float* __restrict__ bqkv,
    const __bf16* __restrict__ WqkvT, __bf16* __restrict__ qkvb)
{
    __shared__ __attribute__((aligned(16))) __bf16 xs[4 * 12 * 512];  // frag-linear [mt][kb][slot][8], slot=lane^(kb&7)
    const int blkM  = blockIdx.x;
    const int which = blockIdx.y;          // 0=q 1=k 2=v
    const int tid = threadIdx.x;
    const int wave = tid >> 6, lane = tid & 63;
    const int l15 = lane & 15, l4 = lane >> 4;

    // stage x (fp32 -> bf16 fragment-linear)
    const float* xb = x + (size_t)blkM * 64 * CDIM;
    for (int i = tid; i < 64 * CDIM / 4; i += 512) {
        float4 v = reinterpret_cast<const float4*>(xb)[i];
        int e = i * 4;
        int row = e / CDIM, c = e % CDIM;
        int mt = row >> 4, kb = c >> 5;
        int lp = (row & 15) + 16 * ((c & 31) >> 3);
        int slot = lp ^ (kb & 7);
        union { __bf16 h[4]; uint2 u; } t;
        t.h[0] = (__bf16)v.x; t.h[1] = (__bf16)v.y; t.h[2] = (__bf16)v.z; t.h[3] = (__bf16)v.w;
        *reinterpret_cast<uint2*>(&xs[((mt * 12 + kb) * 64 + slot) * 8 + (c & 7)]) = t.u;
    }
    __syncthreads();

    const int mt  = wave & 3;
    const int nt0 = (wave >> 2) * 12;
    const __bf16* wbase = WqkvT + (size_t)which * CDIM * CDIM + (size_t)(nt0 * 16 + l15) * CDIM + l4 * 8;

    f32x4 acc[12] = {};
    for (int kb = 0; kb < 12; ++kb) {
        int slot = lane ^ (kb & 7);
        bf16x8 af = *reinterpret_cast<const bf16x8*>(&xs[((mt * 12 + kb) * 64 + slot) * 8]);
        // split 12 into 2x6 to bound live bf registers
#pragma unroll
        for (int i = 0; i < 6; ++i) {
            bf16x8 bf = *reinterpret_cast<const bf16x8*>(wbase + (size_t)i * 16 * CDIM + kb * 32);
            acc[i] = __builtin_amdgcn_mfma_f32_16x16x32_bf16(af, bf, acc[i], 0, 0, 0);
        }
#pragma unroll
        for (int i = 6; i < 12; ++i) {
            bf16x8 bf = *reinterpret_cast<const bf16x8*>(wbase + (size_t)i * 16 * CDIM + kb * 32);
            acc[i] = __builtin_amdgcn_mfma_f32_16x16x32_bf16(af, bf, acc[i], 0, 0, 0);
        }
    }

    const float scl = (which == 0) ? SCALE : 1.0f;
#pragma unroll
    for (int i = 0; i < 12; ++i) {
        int col = (nt0 + i) * 16 + l15;
        float bias = bqkv[which * CDIM + col];
#pragma unroll
        for (int r = 0; r < 4; ++r) {
            size_t row = (size_t)blkM * 64 + mt * 16 + l4 * 4 + r;
            qkvb[row * NQKV + which * CDIM + col] = (__bf16)((acc[i][r] + bias) * scl);
        }
    }
}

// ---------------- K2: attention ----------------
// grid (B, 3): 256 thr = 4 waves; wave = one head (h = blockIdx.y*4 + wave).
// No barriers. P goes through a wave-private 2KB LDS frag (same-wave write->read).
// Pad tokens 49..63 read cross-window garbage: finite, masked (-1e30 cols / P=0 rows).

__global__ __launch_bounds__(256) void attn(
    const __bf16* __restrict__ qkvb, const float* __restrict__ addend,
    __bf16* __restrict__ attnout)
{
    __shared__ __attribute__((aligned(16))) __bf16 ps[4][2][64][8];   // [wave][kb][lane][8]
    const int b = blockIdx.x;
    const int tid = threadIdx.x;
    const int wave = tid >> 6, lane = tid & 63;
    const int l15 = lane & 15, l4 = lane >> 4;
    const int h = blockIdx.y * 4 + wave;
    const int w = b & (NWIN - 1);

    const __bf16* base = qkvb + (size_t)b * NTOK * NQKV;

    // k B-frags (16B/lane, fully coalesced: 16 rows x 64B lines)
    bf16x8 kf[4];
#pragma unroll
    for (int nt = 0; nt < 4; ++nt)
        kf[nt] = *reinterpret_cast<const bf16x8*>(base + (size_t)(nt * 16 + l15) * NQKV + CDIM + h * HD + l4 * 8);

    // vT B-frags (scalar gather; L1 serves the 64B rows)
    bf16x8 vf[2][2];
#pragma unroll
    for (int dt = 0; dt < 2; ++dt)
#pragma unroll
        for (int kb = 0; kb < 2; ++kb)
#pragma unroll
            for (int j = 0; j < 8; ++j) {
                int tok = kb * 32 + l4 * 8 + j;
                vf[dt][kb][j] = base[(size_t)tok * NQKV + 2 * CDIM + h * HD + dt * 16 + l15];
            }

    const float* add_h = addend + (size_t)(w * HEADS + h) * (NTOK * NTOK);

    for (int mt = 0; mt < 4; ++mt) {
        bf16x8 qf = *reinterpret_cast<const bf16x8*>(base + (size_t)(mt * 16 + l15) * NQKV + h * HD + l4 * 8);
        f32x4 s[4];
#pragma unroll
        for (int nt = 0; nt < 4; ++nt) {
            f32x4 z = {};
            s[nt] = __builtin_amdgcn_mfma_f32_16x16x32_bf16(qf, kf[nt], z, 0, 0, 0);
        }

#pragma unroll
        for (int r = 0; r < 4; ++r) {
            int m = mt * 16 + l4 * 4 + r;
            float vals[4];
#pragma unroll
            for (int nt = 0; nt < 4; ++nt) {
                int n = nt * 16 + l15;
                float sv = s[nt][r];
                if (n < NTOK) {
                    if (m < NTOK) sv += add_h[m * NTOK + n];
                } else {
                    sv = -1e30f;
                }
                vals[nt] = sv;
            }
            float mx = fmaxf(fmaxf(vals[0], vals[1]), fmaxf(vals[2], vals[3]));
            mx = fmaxf(mx, __shfl_xor(mx, 1));
            mx = fmaxf(mx, __shfl_xor(mx, 2));
            mx = fmaxf(mx, __shfl_xor(mx, 4));
            mx = fmaxf(mx, __shfl_xor(mx, 8));
            float e0 = __expf(vals[0] - mx);
            float e1 = __expf(vals[1] - mx);
            float e2 = __expf(vals[2] - mx);
            float e3 = __expf(vals[3] - mx);
            float sum = (e0 + e1) + (e2 + e3);
            sum += __shfl_xor(sum, 1);
            sum += __shfl_xor(sum, 2);
            sum += __shfl_xor(sum, 4);
            sum += __shfl_xor(sum, 8);
            float inv = 1.0f / sum;
            float ev[4] = {e0, e1, e2, e3};
#pragma unroll
            for (int nt = 0; nt < 4; ++nt) {
                int lp = (l4 * 4 + r) + 16 * ((nt & 1) * 2 + (l15 >> 3));
                ps[wave][nt >> 1][lp][l15 & 7] = (__bf16)(ev[nt] * inv);
            }
        }

        // PV (wave-local LDS; no barrier needed)
        f32x4 o[2] = {};
#pragma unroll
        for (int kb = 0; kb < 2; ++kb) {
            bf16x8 ap = *reinterpret_cast<const bf16x8*>(&ps[wave][kb][lane][0]);
#pragma unroll
            for (int dt = 0; dt < 2; ++dt)
                o[dt] = __builtin_amdgcn_mfma_f32_16x16x32_bf16(ap, vf[dt][kb], o[dt], 0, 0, 0);
        }
#pragma unroll
        for (int dt = 0; dt < 2; ++dt) {
            int col = h * HD + dt * 16 + l15;
#pragma unroll
            for (int r = 0; r < 4; ++r) {
                int tok = mt * 16 + l4 * 4 + r;
                if (tok < NTOK)
                    attnout[((size_t)b * NTOK + tok) * CDIM + col] = (__bf16)o[dt][r];
            }
        }
    }
}

// ---------------- K3: out projection ----------------

__global__ __launch_bounds__(256, 3) void out_proj(
    const __bf16* __restrict__ A, const __bf16* __restrict__ WoutT,
    const float* __restrict__ bout, float* __restrict__ out)
{
    __shared__ __attribute__((aligned(16))) __bf16 as[4 * 12 * 512];   // frags [mt][kb][slot][8]
    const int blk = blockIdx.x, tid = threadIdx.x;
    const int wave = tid >> 6, lane = tid & 63;
    const int l15 = lane & 15, l4 = lane >> 4;

    const __bf16* Ab = A + (size_t)blk * 64 * CDIM;
    for (int i = tid; i < 64 * CDIM / 8; i += 256) {
        int4 ld = reinterpret_cast<const int4*>(Ab)[i];
        int e = i * 8;
        int row = e / CDIM, c = e % CDIM;
        int mt = row >> 4, kb = c >> 5;
        int lp = (row & 15) + 16 * ((c & 31) >> 3);
        int slot = lp ^ (kb & 7);
        *reinterpret_cast<int4*>(&as[((mt * 12 + kb) * 64 + slot) * 8]) = ld;
    }
    __syncthreads();

    f32x4 acc[6][4] = {};
    for (int kb = 0; kb < 12; ++kb) {
        int slot = lane ^ (kb & 7);
        bf16x8 af[4];
#pragma unroll
        for (int mt = 0; mt < 4; ++mt)
            af[mt] = *reinterpret_cast<const bf16x8*>(&as[((mt * 12 + kb) * 64 + slot) * 8]);
#pragma unroll
        for (int j = 0; j < 6; ++j) {
            int col = (wave * 6 + j) * 16 + l15;
            bf16x8 bf = *reinterpret_cast<const bf16x8*>(WoutT + (size_t)col * CDIM + kb * 32 + l4 * 8);
#pragma unroll
            for (int mt = 0; mt < 4; ++mt)
                acc[j][mt] = __builtin_amdgcn_mfma_f32_16x16x32_bf16(af[mt], bf, acc[j][mt], 0, 0, 0);
        }
    }
#pragma unroll
    for (int j = 0; j < 6; ++j) {
        int col = (wave * 6 + j) * 16 + l15;
        float bias = bout[col];
#pragma unroll
        for (int mt = 0; mt < 4; ++mt) {
#pragma unroll
            for (int r = 0; r < 4; ++r) {
                size_t row = (size_t)blk * 64 + mt * 16 + l4 * 4 + r;
                out[row * CDIM + col] = acc[j][mt][r] + bias;
            }
        }
    }
}

// ---------------- launch ----------------

extern "C" void kernel_launch(void* const* d_in, const int* in_sizes, int n_in,
                              void* d_out, int out_size, void* d_ws, size_t ws_size,
                              hipStream_t stream) {
    (void)n_in; (void)out_size; (void)ws_size;
    const float* x    = (const float*)d_in[0];
    const float* mask = (const float*)d_in[1];
    const float* Wqkv = (const float*)d_in[2];
    const float* bqkv = (const float*)d_in[3];
    const float* Wout = (const float*)d_in[4];
    const float* bout = (const float*)d_in[5];
    const float* rpb  = (const float*)d_in[6];
    const int*   rel  = (const int*)d_in[7];

    const int B = in_sizes[0] / (NTOK * CDIM);   // 4096
    const int M = B * NTOK;                      // 200704

    char* ws = (char*)d_ws;
    __bf16* WqkvT   = (__bf16*)(ws + OFF_WQKVT);
    __bf16* WoutT   = (__bf16*)(ws + OFF_WOUTT);
    float*  addend  = (float*)(ws + OFF_ADDEND);
    __bf16* qkvb    = (__bf16*)(ws + OFF_QKVB);
    __bf16* attnout = (__bf16*)(ws + OFF_ATTNOUT);
    float*  out     = (float*)d_out;

    prep_weights<<<(NQKV * CDIM + 255) / 256, 256, 0, stream>>>(Wqkv, Wout, WqkvT, WoutT);
    prep_addend<<<(NWIN * HEADS * NTOK * NTOK + 255) / 256, 256, 0, stream>>>(rpb, rel, mask, addend);
    qkv_gemm<<<dim3(M / 64, 3), 512, 0, stream>>>(x, bqkv, WqkvT, qkvb);
    attn<<<dim3(B, 3), 256, 0, stream>>>(qkvb, addend, attnout);
    out_proj<<<M / 64, 256, 0, stream>>>(attnout, WoutT, bout, out);
}

// Round 6
// 1036.496 us; speedup vs baseline: 9.6528x; 1.8154x over previous
//
#include <hip/hip_runtime.h>

#define NTOK 49
#define CDIM 384
#define HEADS 12
#define HD 32
#define NWIN 64
#define NQKV 1152
#define SCALE 0.17677669529663687f  // 32^-0.5

typedef __attribute__((ext_vector_type(8))) __bf16 bf16x8;
typedef __attribute__((ext_vector_type(4))) float f32x4;

// workspace offsets (bytes), all 256-aligned
#define OFF_WQKVT   0ull                 // 1152*384 bf16 = 884736
#define OFF_WOUTT   884736ull            // 384*384 bf16  = 294912
#define OFF_ADDEND  1179648ull           // 64*12*49*49 f32 = 7375872
#define OFF_QKVB    8555520ull           // 200704*1152 bf16 = 462422016
#define OFF_ATTNOUT 470977536ull         // 200704*384 bf16 = 154140672
#define OFF_XB      OFF_ATTNOUT          // xb aliases attnout: xb dead before attn writes
// total ~625.1 MB

__device__ __forceinline__ void async_copy16(__bf16* lds_dst, const __bf16* g_src) {
    __builtin_amdgcn_global_load_lds(
        (const __attribute__((address_space(1))) void*)g_src,
        (__attribute__((address_space(3))) void*)lds_dst,
        16, 0, 0);
}

// ---------------- prep kernels ----------------

__global__ void prep_weights(const float* __restrict__ Wqkv, const float* __restrict__ Wout,
                             __bf16* __restrict__ WqkvT, __bf16* __restrict__ WoutT) {
    int idx = blockIdx.x * 256 + threadIdx.x;
    if (idx < NQKV * CDIM) {
        int n = idx / CDIM, k = idx % CDIM;
        WqkvT[idx] = (__bf16)Wqkv[(size_t)k * NQKV + n];
    }
    if (idx < CDIM * CDIM) {
        int n = idx / CDIM, k = idx % CDIM;
        WoutT[idx] = (__bf16)Wout[(size_t)k * CDIM + n];
    }
}

__global__ void prep_addend(const float* __restrict__ rpb, const int* __restrict__ rel,
                            const float* __restrict__ mask, float* __restrict__ addend) {
    int idx = blockIdx.x * 256 + threadIdx.x;
    if (idx >= NWIN * HEADS * NTOK * NTOK) return;
    int mn = idx % (NTOK * NTOK);
    int h  = (idx / (NTOK * NTOK)) % HEADS;
    int w  = idx / (NTOK * NTOK * HEADS);
    addend[idx] = rpb[rel[mn] * HEADS + h] + mask[(size_t)w * NTOK * NTOK + mn];
}

// x fp32 -> bf16, streaming (8 elems / thread / iter)
__global__ __launch_bounds__(256) void prep_xb(const float* __restrict__ x,
                                               __bf16* __restrict__ xb, int total8) {
    int stride = gridDim.x * 256;
    for (int i = blockIdx.x * 256 + threadIdx.x; i < total8; i += stride) {
        float4 a = reinterpret_cast<const float4*>(x)[i * 2];
        float4 b = reinterpret_cast<const float4*>(x)[i * 2 + 1];
        union { __bf16 h[8]; uint4 u; } t;
        t.h[0] = (__bf16)a.x; t.h[1] = (__bf16)a.y; t.h[2] = (__bf16)a.z; t.h[3] = (__bf16)a.w;
        t.h[4] = (__bf16)b.x; t.h[5] = (__bf16)b.y; t.h[6] = (__bf16)b.z; t.h[7] = (__bf16)b.w;
        reinterpret_cast<uint4*>(xb)[i] = t.u;
    }
}

// ---------------- K1: qkv GEMM, m97 structure ----------------
// [M=200704,384] @ [384,1152] -> qkvb bf16 [M][1152]. grid (9 n-tiles, 1568 m-tiles).
// 256 thr = 4 waves; 128x128 tile, BK=64; A,B staged via global_load_lds(16B);
// wave (wr,wc) owns 64x64 quadrant, acc[4][4]; C through swizzled LDS -> 16B stores.

__global__ __launch_bounds__(256) void gemm_qkv(
    const __bf16* __restrict__ xb, const __bf16* __restrict__ WqkvT,
    const float* __restrict__ bqkv, __bf16* __restrict__ qkvb)
{
    __shared__ __attribute__((aligned(16))) __bf16 smem[16384];  // A [0,8192), B [8192,16384); C overlays
    __bf16* As = smem;
    __bf16* Bs = smem + 8192;

    const int n0  = blockIdx.x * 128;
    const int bm0 = blockIdx.y * 128;
    const int tid = threadIdx.x;
    const int wave = tid >> 6, lane = tid & 63;
    const int l15 = lane & 15, l4 = lane >> 4;
    const int wr = wave >> 1, wc = wave & 1;

    f32x4 acc[4][4] = {};

    for (int k0 = 0; k0 < CDIM; k0 += 64) {
        // stage: wave stages chunks c=wave*4+j; chunk c = (tile mt=c>>1, ksub kk=c&1)
#pragma unroll
        for (int j = 0; j < 4; ++j) {
            int c = wave * 4 + j;
            int mt = c >> 1, kk = c & 1;
            const __bf16* sa = xb + (size_t)(bm0 + mt * 16 + l15) * CDIM + k0 + kk * 32 + l4 * 8;
            async_copy16(&As[c * 512], sa);
            const __bf16* sb = WqkvT + (size_t)(n0 + mt * 16 + l15) * CDIM + k0 + kk * 32 + l4 * 8;
            async_copy16(&Bs[c * 512], sb);
        }
        __syncthreads();   // drains vmcnt: staged data visible

#pragma unroll
        for (int kk = 0; kk < 2; ++kk) {
            bf16x8 af[4], bf[4];
#pragma unroll
            for (int mi = 0; mi < 4; ++mi)
                af[mi] = *reinterpret_cast<const bf16x8*>(&As[((wr * 4 + mi) * 2 + kk) * 512 + lane * 8]);
#pragma unroll
            for (int ni = 0; ni < 4; ++ni)
                bf[ni] = *reinterpret_cast<const bf16x8*>(&Bs[((wc * 4 + ni) * 2 + kk) * 512 + lane * 8]);
#pragma unroll
            for (int mi = 0; mi < 4; ++mi)
#pragma unroll
                for (int ni = 0; ni < 4; ++ni)
                    acc[mi][ni] = __builtin_amdgcn_mfma_f32_16x16x32_bf16(af[mi], bf[ni], acc[mi][ni], 0, 0, 0);
        }
        __syncthreads();   // compute reads done before next stage overwrites
    }

    // epilogue: bias (+scale for q), bf16 via swizzled LDS, coalesced 16B stores
    const float scl = (n0 < CDIM) ? SCALE : 1.0f;
    float bias[4];
#pragma unroll
    for (int ni = 0; ni < 4; ++ni)
        bias[ni] = bqkv[n0 + wc * 64 + ni * 16 + l15];

    __bf16* Cs = smem;   // [128][128] bf16, byte ^= ((row>>2)&3)<<5
#pragma unroll
    for (int mi = 0; mi < 4; ++mi)
#pragma unroll
        for (int ni = 0; ni < 4; ++ni)
#pragma unroll
            for (int r = 0; r < 4; ++r) {
                int row = wr * 64 + mi * 16 + l4 * 4 + r;
                int col = wc * 64 + ni * 16 + l15;
                int byte = (row * 256 + col * 2) ^ (((row >> 2) & 3) << 5);
                *reinterpret_cast<__bf16*>(reinterpret_cast<char*>(Cs) + byte) =
                    (__bf16)((acc[mi][ni][r] + bias[ni]) * scl);
            }
    __syncthreads();

#pragma unroll
    for (int it = 0; it < 8; ++it) {
        int idx = it * 4096 + tid * 16;
        int row = idx >> 8, bcol = idx & 255;
        int sb = (row * 256 + bcol) ^ (((row >> 2) & 3) << 5);
        uint4 v = *reinterpret_cast<const uint4*>(reinterpret_cast<const char*>(Cs) + sb);
        *reinterpret_cast<uint4*>(reinterpret_cast<char*>(&qkvb[(size_t)(bm0 + row) * NQKV + n0]) + bcol) = v;
    }
}

// ---------------- K2: attention ----------------
// grid (B, 3): 256 thr = 4 waves; wave = one head. No barriers; wave-private P LDS.

__global__ __launch_bounds__(256) void attn(
    const __bf16* __restrict__ qkvb, const float* __restrict__ addend,
    __bf16* __restrict__ attnout)
{
    __shared__ __attribute__((aligned(16))) __bf16 ps[4][2][64][8];   // [wave][kb][lane][8]
    const int b = blockIdx.x;
    const int tid = threadIdx.x;
    const int wave = tid >> 6, lane = tid & 63;
    const int l15 = lane & 15, l4 = lane >> 4;
    const int h = blockIdx.y * 4 + wave;
    const int w = b & (NWIN - 1);

    const __bf16* base = qkvb + (size_t)b * NTOK * NQKV;

    bf16x8 kf[4];
#pragma unroll
    for (int nt = 0; nt < 4; ++nt)
        kf[nt] = *reinterpret_cast<const bf16x8*>(base + (size_t)(nt * 16 + l15) * NQKV + CDIM + h * HD + l4 * 8);

    bf16x8 vf[2][2];
#pragma unroll
    for (int dt = 0; dt < 2; ++dt)
#pragma unroll
        for (int kb = 0; kb < 2; ++kb)
#pragma unroll
            for (int j = 0; j < 8; ++j) {
                int tok = kb * 32 + l4 * 8 + j;
                vf[dt][kb][j] = base[(size_t)tok * NQKV + 2 * CDIM + h * HD + dt * 16 + l15];
            }

    const float* add_h = addend + (size_t)(w * HEADS + h) * (NTOK * NTOK);

    for (int mt = 0; mt < 4; ++mt) {
        bf16x8 qf = *reinterpret_cast<const bf16x8*>(base + (size_t)(mt * 16 + l15) * NQKV + h * HD + l4 * 8);
        f32x4 s[4];
#pragma unroll
        for (int nt = 0; nt < 4; ++nt) {
            f32x4 z = {};
            s[nt] = __builtin_amdgcn_mfma_f32_16x16x32_bf16(qf, kf[nt], z, 0, 0, 0);
        }

#pragma unroll
        for (int r = 0; r < 4; ++r) {
            int m = mt * 16 + l4 * 4 + r;
            float vals[4];
#pragma unroll
            for (int nt = 0; nt < 4; ++nt) {
                int n = nt * 16 + l15;
                float sv = s[nt][r];
                if (n < NTOK) {
                    if (m < NTOK) sv += add_h[m * NTOK + n];
                } else {
                    sv = -1e30f;
                }
                vals[nt] = sv;
            }
            float mx = fmaxf(fmaxf(vals[0], vals[1]), fmaxf(vals[2], vals[3]));
            mx = fmaxf(mx, __shfl_xor(mx, 1));
            mx = fmaxf(mx, __shfl_xor(mx, 2));
            mx = fmaxf(mx, __shfl_xor(mx, 4));
            mx = fmaxf(mx, __shfl_xor(mx, 8));
            float e0 = __expf(vals[0] - mx);
            float e1 = __expf(vals[1] - mx);
            float e2 = __expf(vals[2] - mx);
            float e3 = __expf(vals[3] - mx);
            float sum = (e0 + e1) + (e2 + e3);
            sum += __shfl_xor(sum, 1);
            sum += __shfl_xor(sum, 2);
            sum += __shfl_xor(sum, 4);
            sum += __shfl_xor(sum, 8);
            float inv = 1.0f / sum;
            float ev[4] = {e0, e1, e2, e3};
#pragma unroll
            for (int nt = 0; nt < 4; ++nt) {
                int lp = (l4 * 4 + r) + 16 * ((nt & 1) * 2 + (l15 >> 3));
                ps[wave][nt >> 1][lp][l15 & 7] = (__bf16)(ev[nt] * inv);
            }
        }

        f32x4 o[2] = {};
#pragma unroll
        for (int kb = 0; kb < 2; ++kb) {
            bf16x8 ap = *reinterpret_cast<const bf16x8*>(&ps[wave][kb][lane][0]);
#pragma unroll
            for (int dt = 0; dt < 2; ++dt)
                o[dt] = __builtin_amdgcn_mfma_f32_16x16x32_bf16(ap, vf[dt][kb], o[dt], 0, 0, 0);
        }
#pragma unroll
        for (int dt = 0; dt < 2; ++dt) {
            int col = h * HD + dt * 16 + l15;
#pragma unroll
            for (int r = 0; r < 4; ++r) {
                int tok = mt * 16 + l4 * 4 + r;
                if (tok < NTOK)
                    attnout[((size_t)b * NTOK + tok) * CDIM + col] = (__bf16)o[dt][r];
            }
        }
    }
}

// ---------------- K3: out projection (unchanged) ----------------

__global__ __launch_bounds__(256, 3) void out_proj(
    const __bf16* __restrict__ A, const __bf16* __restrict__ WoutT,
    const float* __restrict__ bout, float* __restrict__ out)
{
    __shared__ __attribute__((aligned(16))) __bf16 as[4 * 12 * 512];   // frags [mt][kb][slot][8]
    const int blk = blockIdx.x, tid = threadIdx.x;
    const int wave = tid >> 6, lane = tid & 63;
    const int l15 = lane & 15, l4 = lane >> 4;

    const __bf16* Ab = A + (size_t)blk * 64 * CDIM;
    for (int i = tid; i < 64 * CDIM / 8; i += 256) {
        int4 ld = reinterpret_cast<const int4*>(Ab)[i];
        int e = i * 8;
        int row = e / CDIM, c = e % CDIM;
        int mt = row >> 4, kb = c >> 5;
        int lp = (row & 15) + 16 * ((c & 31) >> 3);
        int slot = lp ^ (kb & 7);
        *reinterpret_cast<int4*>(&as[((mt * 12 + kb) * 64 + slot) * 8]) = ld;
    }
    __syncthreads();

    f32x4 acc[6][4] = {};
    for (int kb = 0; kb < 12; ++kb) {
        int slot = lane ^ (kb & 7);
        bf16x8 af[4];
#pragma unroll
        for (int mt = 0; mt < 4; ++mt)
            af[mt] = *reinterpret_cast<const bf16x8*>(&as[((mt * 12 + kb) * 64 + slot) * 8]);
#pragma unroll
        for (int j = 0; j < 6; ++j) {
            int col = (wave * 6 + j) * 16 + l15;
            bf16x8 bf = *reinterpret_cast<const bf16x8*>(WoutT + (size_t)col * CDIM + kb * 32 + l4 * 8);
#pragma unroll
            for (int mt = 0; mt < 4; ++mt)
                acc[j][mt] = __builtin_amdgcn_mfma_f32_16x16x32_bf16(af[mt], bf, acc[j][mt], 0, 0, 0);
        }
    }
#pragma unroll
    for (int j = 0; j < 6; ++j) {
        int col = (wave * 6 + j) * 16 + l15;
        float bias = bout[col];
#pragma unroll
        for (int mt = 0; mt < 4; ++mt) {
#pragma unroll
            for (int r = 0; r < 4; ++r) {
                size_t row = (size_t)blk * 64 + mt * 16 + l4 * 4 + r;
                out[row * CDIM + col] = acc[j][mt][r] + bias;
            }
        }
    }
}

// ---------------- launch ----------------

extern "C" void kernel_launch(void* const* d_in, const int* in_sizes, int n_in,
                              void* d_out, int out_size, void* d_ws, size_t ws_size,
                              hipStream_t stream) {
    (void)n_in; (void)out_size; (void)ws_size;
    const float* x    = (const float*)d_in[0];
    const float* mask = (const float*)d_in[1];
    const float* Wqkv = (const float*)d_in[2];
    const float* bqkv = (const float*)d_in[3];
    const float* Wout = (const float*)d_in[4];
    const float* bout = (const float*)d_in[5];
    const float* rpb  = (const float*)d_in[6];
    const int*   rel  = (const int*)d_in[7];

    const int B = in_sizes[0] / (NTOK * CDIM);   // 4096
    const int M = B * NTOK;                      // 200704

    char* ws = (char*)d_ws;
    __bf16* WqkvT   = (__bf16*)(ws + OFF_WQKVT);
    __bf16* WoutT   = (__bf16*)(ws + OFF_WOUTT);
    float*  addend  = (float*)(ws + OFF_ADDEND);
    __bf16* qkvb    = (__bf16*)(ws + OFF_QKVB);
    __bf16* xb      = (__bf16*)(ws + OFF_XB);       // aliases attnout (xb dead before attn)
    __bf16* attnout = (__bf16*)(ws + OFF_ATTNOUT);
    float*  out     = (float*)d_out;

    prep_weights<<<(NQKV * CDIM + 255) / 256, 256, 0, stream>>>(Wqkv, Wout, WqkvT, WoutT);
    prep_addend<<<(NWIN * HEADS * NTOK * NTOK + 255) / 256, 256, 0, stream>>>(rpb, rel, mask, addend);
    prep_xb<<<2048, 256, 0, stream>>>(x, xb, M * CDIM / 8);
    gemm_qkv<<<dim3(NQKV / 128, M / 128), 256, 0, stream>>>(xb, WqkvT, bqkv, qkvb);
    attn<<<dim3(B, 3), 256, 0, stream>>>(qkvb, addend, attnout);
    out_proj<<<M / 64, 256, 0, stream>>>(attnout, WoutT, bout, out);
}

// Round 7
// 939.852 us; speedup vs baseline: 10.6454x; 1.1028x over previous
//
#include <hip/hip_runtime.h>

#define NTOK 49
#define CDIM 384
#define HEADS 12
#define HD 32
#define NWIN 64
#define NQKV 1152
#define SCALE 0.17677669529663687f  // 32^-0.5

typedef __attribute__((ext_vector_type(8))) __bf16 bf16x8;
typedef __attribute__((ext_vector_type(4))) float f32x4;

// workspace offsets (bytes), all 256-aligned
#define OFF_WQKVT   0ull                 // 1152*384 bf16 = 884736
#define OFF_WOUTT   884736ull            // 384*384 bf16  = 294912
#define OFF_ADDEND  1179648ull           // 64*12*49*49 f32 = 7375872
#define OFF_QKVB    8555520ull           // 200704*1152 bf16 = 462422016
#define OFF_ATTNOUT 470977536ull         // 200704*384 bf16 = 154140672
#define OFF_XB      OFF_ATTNOUT          // xb aliases attnout: xb dead before attn writes
// total ~625.1 MB

__device__ __forceinline__ void async_copy16(__bf16* lds_dst, const __bf16* g_src) {
    __builtin_amdgcn_global_load_lds(
        (const __attribute__((address_space(1))) void*)g_src,
        (__attribute__((address_space(3))) void*)lds_dst,
        16, 0, 0);
}

// ---------------- prep kernels ----------------

__global__ void prep_weights(const float* __restrict__ Wqkv, const float* __restrict__ Wout,
                             __bf16* __restrict__ WqkvT, __bf16* __restrict__ WoutT) {
    int idx = blockIdx.x * 256 + threadIdx.x;
    if (idx < NQKV * CDIM) {
        int n = idx / CDIM, k = idx % CDIM;
        WqkvT[idx] = (__bf16)Wqkv[(size_t)k * NQKV + n];
    }
    if (idx < CDIM * CDIM) {
        int n = idx / CDIM, k = idx % CDIM;
        WoutT[idx] = (__bf16)Wout[(size_t)k * CDIM + n];
    }
}

__global__ void prep_addend(const float* __restrict__ rpb, const int* __restrict__ rel,
                            const float* __restrict__ mask, float* __restrict__ addend) {
    int idx = blockIdx.x * 256 + threadIdx.x;
    if (idx >= NWIN * HEADS * NTOK * NTOK) return;
    int mn = idx % (NTOK * NTOK);
    int h  = (idx / (NTOK * NTOK)) % HEADS;
    int w  = idx / (NTOK * NTOK * HEADS);
    addend[idx] = rpb[rel[mn] * HEADS + h] + mask[(size_t)w * NTOK * NTOK + mn];
}

// x fp32 -> bf16, streaming (8 elems / thread / iter)
__global__ __launch_bounds__(256) void prep_xb(const float* __restrict__ x,
                                               __bf16* __restrict__ xb, int total8) {
    int stride = gridDim.x * 256;
    for (int i = blockIdx.x * 256 + threadIdx.x; i < total8; i += stride) {
        float4 a = reinterpret_cast<const float4*>(x)[i * 2];
        float4 b = reinterpret_cast<const float4*>(x)[i * 2 + 1];
        union { __bf16 h[8]; uint4 u; } t;
        t.h[0] = (__bf16)a.x; t.h[1] = (__bf16)a.y; t.h[2] = (__bf16)a.z; t.h[3] = (__bf16)a.w;
        t.h[4] = (__bf16)b.x; t.h[5] = (__bf16)b.y; t.h[6] = (__bf16)b.z; t.h[7] = (__bf16)b.w;
        reinterpret_cast<uint4*>(xb)[i] = t.u;
    }
}

// ---------------- K1: qkv GEMM, m97 structure + XCD swizzle ----------------
// [M=200704,384] @ [384,1152] -> qkvb bf16 [M][1152]. 1D grid 14112 blocks.
// Linear order n-fastest (lid = m*9 + n); bijective XCD chunking (14112%8==0)
// puts all 9 n-blocks sharing an A-tile on one XCD L2.
// 256 thr = 4 waves; 128x128 tile, BK=64; A,B via global_load_lds(16B);
// wave (wr,wc) owns 64x64 quadrant, acc[4][4]; C through swizzled LDS -> 16B stores.
// __launch_bounds__(256,3): 3 waves/EU -> reg cap ~170 (need ~152) -> 3 blocks/CU.

__global__ __launch_bounds__(256, 3) void gemm_qkv(
    const __bf16* __restrict__ xb, const __bf16* __restrict__ WqkvT,
    const float* __restrict__ bqkv, __bf16* __restrict__ qkvb)
{
    __shared__ __attribute__((aligned(16))) __bf16 smem[16384];  // A [0,8192), B [8192,16384); C overlays
    __bf16* As = smem;
    __bf16* Bs = smem + 8192;

    // bijective XCD-chunk swizzle: nwg = 14112 = 8 * 1764
    const int cpx  = 14112 >> 3;                     // 1764
    const int lid  = (blockIdx.x & 7) * cpx + (blockIdx.x >> 3);
    const int mblk = lid / 9, nblk = lid % 9;
    const int n0  = nblk * 128;
    const int bm0 = mblk * 128;

    const int tid = threadIdx.x;
    const int wave = tid >> 6, lane = tid & 63;
    const int l15 = lane & 15, l4 = lane >> 4;
    const int wr = wave >> 1, wc = wave & 1;

    f32x4 acc[4][4] = {};

    for (int k0 = 0; k0 < CDIM; k0 += 64) {
        // stage: wave stages chunks c=wave*4+j; chunk c = (tile mt=c>>1, ksub kk=c&1)
#pragma unroll
        for (int j = 0; j < 4; ++j) {
            int c = wave * 4 + j;
            int mt = c >> 1, kk = c & 1;
            const __bf16* sa = xb + (size_t)(bm0 + mt * 16 + l15) * CDIM + k0 + kk * 32 + l4 * 8;
            async_copy16(&As[c * 512], sa);
            const __bf16* sb = WqkvT + (size_t)(n0 + mt * 16 + l15) * CDIM + k0 + kk * 32 + l4 * 8;
            async_copy16(&Bs[c * 512], sb);
        }
        __syncthreads();   // drains vmcnt: staged data visible

#pragma unroll
        for (int kk = 0; kk < 2; ++kk) {
            bf16x8 af[4], bf[4];
#pragma unroll
            for (int mi = 0; mi < 4; ++mi)
                af[mi] = *reinterpret_cast<const bf16x8*>(&As[((wr * 4 + mi) * 2 + kk) * 512 + lane * 8]);
#pragma unroll
            for (int ni = 0; ni < 4; ++ni)
                bf[ni] = *reinterpret_cast<const bf16x8*>(&Bs[((wc * 4 + ni) * 2 + kk) * 512 + lane * 8]);
#pragma unroll
            for (int mi = 0; mi < 4; ++mi)
#pragma unroll
                for (int ni = 0; ni < 4; ++ni)
                    acc[mi][ni] = __builtin_amdgcn_mfma_f32_16x16x32_bf16(af[mi], bf[ni], acc[mi][ni], 0, 0, 0);
        }
        __syncthreads();   // compute reads done before next stage overwrites
    }

    // epilogue: bias (+scale for q), bf16 via swizzled LDS, coalesced 16B stores
    const float scl = (n0 < CDIM) ? SCALE : 1.0f;
    float bias[4];
#pragma unroll
    for (int ni = 0; ni < 4; ++ni)
        bias[ni] = bqkv[n0 + wc * 64 + ni * 16 + l15];

    __bf16* Cs = smem;   // [128][128] bf16, byte ^= ((row>>2)&3)<<5
#pragma unroll
    for (int mi = 0; mi < 4; ++mi)
#pragma unroll
        for (int ni = 0; ni < 4; ++ni)
#pragma unroll
            for (int r = 0; r < 4; ++r) {
                int row = wr * 64 + mi * 16 + l4 * 4 + r;
                int col = wc * 64 + ni * 16 + l15;
                int byte = (row * 256 + col * 2) ^ (((row >> 2) & 3) << 5);
                *reinterpret_cast<__bf16*>(reinterpret_cast<char*>(Cs) + byte) =
                    (__bf16)((acc[mi][ni][r] + bias[ni]) * scl);
            }
    __syncthreads();

#pragma unroll
    for (int it = 0; it < 8; ++it) {
        int idx = it * 4096 + tid * 16;
        int row = idx >> 8, bcol = idx & 255;
        int sb = (row * 256 + bcol) ^ (((row >> 2) & 3) << 5);
        uint4 v = *reinterpret_cast<const uint4*>(reinterpret_cast<const char*>(Cs) + sb);
        *reinterpret_cast<uint4*>(reinterpret_cast<char*>(&qkvb[(size_t)(bm0 + row) * NQKV + n0]) + bcol) = v;
    }
}

// ---------------- K2: attention ----------------
// grid (B, 3): 256 thr = 4 waves; wave = one head. No barriers; wave-private P LDS.

__global__ __launch_bounds__(256) void attn(
    const __bf16* __restrict__ qkvb, const float* __restrict__ addend,
    __bf16* __restrict__ attnout)
{
    __shared__ __attribute__((aligned(16))) __bf16 ps[4][2][64][8];   // [wave][kb][lane][8]
    const int b = blockIdx.x;
    const int tid = threadIdx.x;
    const int wave = tid >> 6, lane = tid & 63;
    const int l15 = lane & 15, l4 = lane >> 4;
    const int h = blockIdx.y * 4 + wave;
    const int w = b & (NWIN - 1);

    const __bf16* base = qkvb + (size_t)b * NTOK * NQKV;

    bf16x8 kf[4];
#pragma unroll
    for (int nt = 0; nt < 4; ++nt)
        kf[nt] = *reinterpret_cast<const bf16x8*>(base + (size_t)(nt * 16 + l15) * NQKV + CDIM + h * HD + l4 * 8);

    bf16x8 vf[2][2];
#pragma unroll
    for (int dt = 0; dt < 2; ++dt)
#pragma unroll
        for (int kb = 0; kb < 2; ++kb)
#pragma unroll
            for (int j = 0; j < 8; ++j) {
                int tok = kb * 32 + l4 * 8 + j;
                vf[dt][kb][j] = base[(size_t)tok * NQKV + 2 * CDIM + h * HD + dt * 16 + l15];
            }

    const float* add_h = addend + (size_t)(w * HEADS + h) * (NTOK * NTOK);

    for (int mt = 0; mt < 4; ++mt) {
        bf16x8 qf = *reinterpret_cast<const bf16x8*>(base + (size_t)(mt * 16 + l15) * NQKV + h * HD + l4 * 8);
        f32x4 s[4];
#pragma unroll
        for (int nt = 0; nt < 4; ++nt) {
            f32x4 z = {};
            s[nt] = __builtin_amdgcn_mfma_f32_16x16x32_bf16(qf, kf[nt], z, 0, 0, 0);
        }

#pragma unroll
        for (int r = 0; r < 4; ++r) {
            int m = mt * 16 + l4 * 4 + r;
            float vals[4];
#pragma unroll
            for (int nt = 0; nt < 4; ++nt) {
                int n = nt * 16 + l15;
                float sv = s[nt][r];
                if (n < NTOK) {
                    if (m < NTOK) sv += add_h[m * NTOK + n];
                } else {
                    sv = -1e30f;
                }
                vals[nt] = sv;
            }
            float mx = fmaxf(fmaxf(vals[0], vals[1]), fmaxf(vals[2], vals[3]));
            mx = fmaxf(mx, __shfl_xor(mx, 1));
            mx = fmaxf(mx, __shfl_xor(mx, 2));
            mx = fmaxf(mx, __shfl_xor(mx, 4));
            mx = fmaxf(mx, __shfl_xor(mx, 8));
            float e0 = __expf(vals[0] - mx);
            float e1 = __expf(vals[1] - mx);
            float e2 = __expf(vals[2] - mx);
            float e3 = __expf(vals[3] - mx);
            float sum = (e0 + e1) + (e2 + e3);
            sum += __shfl_xor(sum, 1);
            sum += __shfl_xor(sum, 2);
            sum += __shfl_xor(sum, 4);
            sum += __shfl_xor(sum, 8);
            float inv = 1.0f / sum;
            float ev[4] = {e0, e1, e2, e3};
#pragma unroll
            for (int nt = 0; nt < 4; ++nt) {
                int lp = (l4 * 4 + r) + 16 * ((nt & 1) * 2 + (l15 >> 3));
                ps[wave][nt >> 1][lp][l15 & 7] = (__bf16)(ev[nt] * inv);
            }
        }

        f32x4 o[2] = {};
#pragma unroll
        for (int kb = 0; kb < 2; ++kb) {
            bf16x8 ap = *reinterpret_cast<const bf16x8*>(&ps[wave][kb][lane][0]);
#pragma unroll
            for (int dt = 0; dt < 2; ++dt)
                o[dt] = __builtin_amdgcn_mfma_f32_16x16x32_bf16(ap, vf[dt][kb], o[dt], 0, 0, 0);
        }
#pragma unroll
        for (int dt = 0; dt < 2; ++dt) {
            int col = h * HD + dt * 16 + l15;
#pragma unroll
            for (int r = 0; r < 4; ++r) {
                int tok = mt * 16 + l4 * 4 + r;
                if (tok < NTOK)
                    attnout[((size_t)b * NTOK + tok) * CDIM + col] = (__bf16)o[dt][r];
            }
        }
    }
}

// ---------------- K3: out projection (unchanged) ----------------

__global__ __launch_bounds__(256, 3) void out_proj(
    const __bf16* __restrict__ A, const __bf16* __restrict__ WoutT,
    const float* __restrict__ bout, float* __restrict__ out)
{
    __shared__ __attribute__((aligned(16))) __bf16 as[4 * 12 * 512];   // frags [mt][kb][slot][8]
    const int blk = blockIdx.x, tid = threadIdx.x;
    const int wave = tid >> 6, lane = tid & 63;
    const int l15 = lane & 15, l4 = lane >> 4;

    const __bf16* Ab = A + (size_t)blk * 64 * CDIM;
    for (int i = tid; i < 64 * CDIM / 8; i += 256) {
        int4 ld = reinterpret_cast<const int4*>(Ab)[i];
        int e = i * 8;
        int row = e / CDIM, c = e % CDIM;
        int mt = row >> 4, kb = c >> 5;
        int lp = (row & 15) + 16 * ((c & 31) >> 3);
        int slot = lp ^ (kb & 7);
        *reinterpret_cast<int4*>(&as[((mt * 12 + kb) * 64 + slot) * 8]) = ld;
    }
    __syncthreads();

    f32x4 acc[6][4] = {};
    for (int kb = 0; kb < 12; ++kb) {
        int slot = lane ^ (kb & 7);
        bf16x8 af[4];
#pragma unroll
        for (int mt = 0; mt < 4; ++mt)
            af[mt] = *reinterpret_cast<const bf16x8*>(&as[((mt * 12 + kb) * 64 + slot) * 8]);
#pragma unroll
        for (int j = 0; j < 6; ++j) {
            int col = (wave * 6 + j) * 16 + l15;
            bf16x8 bf = *reinterpret_cast<const bf16x8*>(WoutT + (size_t)col * CDIM + kb * 32 + l4 * 8);
#pragma unroll
            for (int mt = 0; mt < 4; ++mt)
                acc[j][mt] = __builtin_amdgcn_mfma_f32_16x16x32_bf16(af[mt], bf, acc[j][mt], 0, 0, 0);
        }
    }
#pragma unroll
    for (int j = 0; j < 6; ++j) {
        int col = (wave * 6 + j) * 16 + l15;
        float bias = bout[col];
#pragma unroll
        for (int mt = 0; mt < 4; ++mt) {
#pragma unroll
            for (int r = 0; r < 4; ++r) {
                size_t row = (size_t)blk * 64 + mt * 16 + l4 * 4 + r;
                out[row * CDIM + col] = acc[j][mt][r] + bias;
            }
        }
    }
}

// ---------------- launch ----------------

extern "C" void kernel_launch(void* const* d_in, const int* in_sizes, int n_in,
                              void* d_out, int out_size, void* d_ws, size_t ws_size,
                              hipStream_t stream) {
    (void)n_in; (void)out_size; (void)ws_size;
    const float* x    = (const float*)d_in[0];
    const float* mask = (const float*)d_in[1];
    const float* Wqkv = (const float*)d_in[2];
    const float* bqkv = (const float*)d_in[3];
    const float* Wout = (const float*)d_in[4];
    const float* bout = (const float*)d_in[5];
    const float* rpb  = (const float*)d_in[6];
    const int*   rel  = (const int*)d_in[7];

    const int B = in_sizes[0] / (NTOK * CDIM);   // 4096
    const int M = B * NTOK;                      // 200704

    char* ws = (char*)d_ws;
    __bf16* WqkvT   = (__bf16*)(ws + OFF_WQKVT);
    __bf16* WoutT   = (__bf16*)(ws + OFF_WOUTT);
    float*  addend  = (float*)(ws + OFF_ADDEND);
    __bf16* qkvb    = (__bf16*)(ws + OFF_QKVB);
    __bf16* xb      = (__bf16*)(ws + OFF_XB);       // aliases attnout (xb dead before attn)
    __bf16* attnout = (__bf16*)(ws + OFF_ATTNOUT);
    float*  out     = (float*)d_out;

    prep_weights<<<(NQKV * CDIM + 255) / 256, 256, 0, stream>>>(Wqkv, Wout, WqkvT, WoutT);
    prep_addend<<<(NWIN * HEADS * NTOK * NTOK + 255) / 256, 256, 0, stream>>>(rpb, rel, mask, addend);
    prep_xb<<<2048, 256, 0, stream>>>(x, xb, M * CDIM / 8);
    gemm_qkv<<<(M / 128) * (NQKV / 128), 256, 0, stream>>>(xb, WqkvT, bqkv, qkvb);
    attn<<<dim3(B, 3), 256, 0, stream>>>(qkvb, addend, attnout);
    out_proj<<<M / 64, 256, 0, stream>>>(attnout, WoutT, bout, out);
}